// Round 5
// baseline (633.952 us; speedup 1.0000x reference)
//
#include <hip/hip_runtime.h>

// Problem constants
#define H_    128
#define W_    128
#define C_    3
#define PAD_  10
#define LWID  117          // LW = LH = 117
#define L_    13689        // LH*LW
#define LPAD  13696        // 107 * 128
#define D_    3072         // C*KH*KW
#define NMEM_ 4096

#define T_MARGIN 3.0f      // candidate margin; i8-quant score err sigma ~0.32 (9 sigma)
#define CAP_     256       // per-row candidate list capacity (expected ~70)
#define SCAP_    64        // rescue shortlist capacity (expected ~1.4)

#define PSCALE 127.0f      // patch quant scale (p in [0,1))
#define MSCALE 32.0f       // mem quant scale (clip +-3.97)
#define INVS   (1.0f / (PSCALE * MSCALE))

typedef int   intx4  __attribute__((ext_vector_type(4)));

// Static device-side scratch (bss) — no d_ws dependency
__device__ int                g_best[L_];
__device__ int                g_pat[L_];     // mapping[g_best[l]] resolved in rescue
__device__ float              g_bias[NMEM_];
__device__ unsigned           g_max;
__device__ int                g_cnt[LPAD];
__device__ unsigned long long g_list[(size_t)LPAD * CAP_];   // 28 MB
__device__ char               g_A[(size_t)LPAD * D_];        // 42 MB i8 patches
__device__ char               g_B[(size_t)NMEM_ * D_];       // 12.6 MB i8 mem
__device__ float              g_part[4][H_ * W_ * C_];       // fold partials, 786 KB

__device__ __forceinline__ unsigned sortable(float f) {
    unsigned b = __float_as_uint(f);
    return (b & 0x80000000u) ? ~b : (b | 0x80000000u);
}
__device__ __forceinline__ float unsortable(unsigned u) {
    unsigned b = (u & 0x80000000u) ? (u & 0x7FFFFFFFu) : ~u;
    return __uint_as_float(b);
}
__device__ __forceinline__ unsigned long long packkey(float s, int n) {
    // max-key == max score; ties -> smaller n (jnp.argmax first-index)
    return ((unsigned long long)sortable(s) << 32) | (unsigned)(~n);
}

// async global->LDS, 16 bytes per lane (global_load_lds_dwordx4)
__device__ __forceinline__ void gl_lds16(const char* g, char* l) {
    __builtin_amdgcn_global_load_lds(
        (const __attribute__((address_space(1))) unsigned int*)(g),
        (__attribute__((address_space(3))) unsigned int*)(l), 16, 0, 0);
}

__device__ __forceinline__ int pack4(int a, int b, int c, int d) {
    return (a & 255) | ((b & 255) << 8) | ((c & 255) << 16) | ((d & 255) << 24);
}

// ---- fused prep: quantize mem + bias | build+quantize patches | zero cnts ---
__global__ __launch_bounds__(256)
void prep(const float* __restrict__ img, const float* __restrict__ mem)
{
    const int b = blockIdx.x;
    if (b < NMEM_) {
        const int n = b;
        const float4* row = (const float4*)(mem + (size_t)n * D_);
        int* q8 = (int*)(g_B + (size_t)n * D_);
        float s = 0.f;
        for (int q = threadIdx.x; q < D_ / 4; q += 256) {
            float4 v = row[q];
            int q0 = __float2int_rn(fminf(fmaxf(v.x * MSCALE, -127.f), 127.f));
            int q1 = __float2int_rn(fminf(fmaxf(v.y * MSCALE, -127.f), 127.f));
            int q2 = __float2int_rn(fminf(fmaxf(v.z * MSCALE, -127.f), 127.f));
            int q3 = __float2int_rn(fminf(fmaxf(v.w * MSCALE, -127.f), 127.f));
            q8[q] = pack4(q0, q1, q2, q3);
            s = fmaf(v.x, v.x, s); s = fmaf(v.y, v.y, s);
            s = fmaf(v.z, v.z, s); s = fmaf(v.w, v.w, s);
        }
        #pragma unroll
        for (int m = 32; m >= 1; m >>= 1) s += __shfl_down(s, m, 64);
        __shared__ float red[4];
        int lane = threadIdx.x & 63, w = threadIdx.x >> 6;
        if (lane == 0) red[w] = s;
        __syncthreads();
        if (threadIdx.x == 0) g_bias[n] = -0.5f * (red[0] + red[1] + red[2] + red[3]);
    } else {
        const int l = b - NMEM_;            // 0..LPAD-1 (pad rows -> zeros)
        if (threadIdx.x == 0) { g_cnt[l] = 0; if (l == 0) g_max = 0u; }
        const int py = l / LWID, px = l - (l / LWID) * LWID;
        const bool vl = l < L_;
        int* q8 = (int*)(g_A + (size_t)l * D_);
        for (int q = threadIdx.x; q < D_ / 4; q += 256) {
            int d = q * 4;
            int c = d >> 10, rem = d & 1023, kh = rem >> 5, kw0 = rem & 31;
            int qv[4] = {0, 0, 0, 0};
            if (vl) {
                int y = py + kh - PAD_;
                if ((unsigned)y < (unsigned)H_) {
                    int xb = px + kw0 - PAD_;
                    const float* ip = img + (size_t)y * (W_ * C_) + c;
                    #pragma unroll
                    for (int t = 0; t < 4; t++) {
                        int x = xb + t;
                        if ((unsigned)x < (unsigned)W_)
                            qv[t] = __float2int_rn(ip[x * C_] * PSCALE);
                    }
                }
            }
            q8[q] = pack4(qv[0], qv[1], qv[2], qv[3]);
        }
    }
}

// ---- i8 MFMA GEMM, 128l x 256n tile, BK=128 -------------------------------
// Round-5: A direct global->VGPR (no LDS round-trip for A). Pipe arithmetic
// per block-K-step per CU: MFMA = 256 x 5.1 = 1306 cyc; LDS was A(16KB w +
// 32KB r) + B(32KB w + 64KB r) = 144KB @ ~112 B/cyc = 1290 cyc — co-critical
// with MFMA, which is why rounds 1-3's scheduling changes were all flat.
// A-fragment loads are naturally coalescible from the row-major layout: a
// wave's 64 lanes (mrow 0..15 x kgrp 0..3) cover 16 rows x one full 64B line
// (4 lanes x 16B per line) -> 100% line utilization, no overfetch. LDS drops
// to B-only 96KB/step (~860-1150 cyc) < MFMA -> MFMA becomes sole critical
// pipe. A loads issue BEFORE B staging so the existing barrier vmcnt drain
// covers them at no extra stall. B path / swizzle / epilogue unchanged.
__global__ __launch_bounds__(256, 2)
void gemm_scores()
{
    __shared__ char sB[256 * 128];   // 32 KB
    __shared__ float biasS[256];

    const int tid = threadIdx.x;
    const int b = blockIdx.x;
    const int nt = (b & 7) * 2 + ((b >> 3) & 1);   // 0..15
    const int lt = b >> 4;                          // 0..106
    const int l0 = lt * 128;
    const int n0 = nt * 256;

    biasS[tid] = g_bias[n0 + tid];

    const int wave = tid >> 6, lane = tid & 63;
    const int wy = wave >> 1, wx = wave & 1;      // wave tile: 64l x 128n
    const int mrow = lane & 15, kgrp = lane >> 4;

    intx4 acc[4][8];
    #pragma unroll
    for (int i = 0; i < 4; i++)
        #pragma unroll
        for (int j = 0; j < 8; j++) acc[i][j] = (intx4){0, 0, 0, 0};

    // per-lane A base: row = l0 + wy*64 + mrow, col-chunk = kgrp*16
    const char* Arow = g_A + (size_t)(l0 + wy * 64 + mrow) * D_ + kgrp * 16;
    const char* Bb   = g_B + (size_t)n0 * D_;

    // B staging: 2048 16B-chunks per iter. Chunk c -> row=c>>3,
    // sub-block jj=(c&7)^(row&7) (XOR swizzle; conflicts -> 0).
    for (int d0 = 0; d0 < D_; d0 += 128) {
        __syncthreads();
        // A fragments for this K-step, direct to VGPR (ks0 then ks1 batches).
        intx4 a0[4], a1[4];
        #pragma unroll
        for (int i = 0; i < 4; i++)
            a0[i] = *(const intx4*)(Arow + (size_t)(i * 16) * D_ + d0);
        #pragma unroll
        for (int t = 0; t < 8; t++) {
            int c = tid + 256 * t;
            int row = c >> 3;
            int jj = (c & 7) ^ (row & 7);
            gl_lds16(Bb + (size_t)row * D_ + d0 + jj * 16, &sB[c * 16]);
        }
        #pragma unroll
        for (int i = 0; i < 4; i++)
            a1[i] = *(const intx4*)(Arow + (size_t)(i * 16) * D_ + d0 + 64);
        __syncthreads();   // drains vmcnt(0): A regs + B LDS both ready

        #pragma unroll
        for (int ks = 0; ks < 2; ks++) {
            intx4 bf[8];
            #pragma unroll
            for (int j = 0; j < 8; j++) {
                int rb = wx * 128 + j * 16 + mrow;
                int cb = rb * 8 + ((ks * 4 + kgrp) ^ (rb & 7));
                bf[j] = *(const intx4*)&sB[cb * 16];
            }
            #pragma unroll
            for (int i = 0; i < 4; i++)
                #pragma unroll
                for (int j = 0; j < 8; j++)
                    acc[i][j] = __builtin_amdgcn_mfma_i32_16x16x64_i8(
                        ks ? a1[i] : a0[i], bf[j], acc[i][j], 0, 0, 0);
        }
    }

    // epilogue. C/D layout: col = lane&15 (mrow), row = kgrp*4 + reg.
    #pragma unroll
    for (int i = 0; i < 4; i++) {
        #pragma unroll
        for (int r = 0; r < 4; r++) {
            const int lrow = l0 + wy * 64 + i * 16 + kgrp * 4 + r;
            float sc[8];
            #pragma unroll
            for (int j = 0; j < 8; j++)
                sc[j] = (float)acc[i][j][r] * INVS + biasS[wx * 128 + j * 16 + mrow];
            float bestv = sc[0]; int bestj = 0;
            #pragma unroll
            for (int j = 1; j < 8; j++)
                if (sc[j] > bestv) { bestv = sc[j]; bestj = j; }
            unsigned long long key = packkey(bestv, n0 + wx * 128 + bestj * 16 + mrow);
            // 16-lane group max -> covers the wave's full 128-col n-range
            #pragma unroll
            for (int m = 1; m < 16; m <<= 1) {
                unsigned long long o = __shfl_xor(key, m, 64);
                if (o > key) key = o;
            }
            float thr = unsortable((unsigned)(key >> 32)) - T_MARGIN;
            #pragma unroll
            for (int j = 0; j < 8; j++) {
                if (sc[j] >= thr) {
                    int pos = atomicAdd(&g_cnt[lrow], 1);
                    if (pos < CAP_)
                        g_list[(size_t)lrow * CAP_ + pos] =
                            packkey(sc[j], n0 + wx * 128 + j * 16 + mrow);
                }
            }
        }
    }
}

// ---- per-row shortlist + exact fp32 rescore + pattern resolve ---------------
// kk==1 early exit (round-4, verified): a single shortlist candidate IS the
// argmax — skip the 12KB mem-row read + img gathers. Bit-identical output.
__global__ __launch_bounds__(256)
void reduce_rescue(const float* __restrict__ img, const float* __restrict__ mem,
                   const int* __restrict__ mapping)
{
    const int l = blockIdx.x;
    const int tid = threadIdx.x;
    const int lane = tid & 63, wave = tid >> 6;

    __shared__ unsigned long long redk[4];
    __shared__ float redf[4];
    __shared__ int   scand[SCAP_];
    __shared__ int   scnt;

    if (tid == 0) scnt = 0;
    int cnt = g_cnt[l];
    bool full = cnt > CAP_;
    __syncthreads();

    if (!full) {
        int k = cnt;
        const unsigned long long* lst = g_list + (size_t)l * CAP_;
        unsigned long long mk = 0ull;
        for (int q = tid; q < k; q += 256) {
            unsigned long long e = lst[q];
            if (e > mk) mk = e;
        }
        #pragma unroll
        for (int m = 32; m >= 1; m >>= 1) {
            unsigned long long o = __shfl_xor(mk, m, 64);
            if (o > mk) mk = o;
        }
        if (lane == 0) redk[wave] = mk;
        __syncthreads();
        unsigned long long rowk = redk[0];
        #pragma unroll
        for (int w = 1; w < 4; w++) if (redk[w] > rowk) rowk = redk[w];
        float thr = unsortable((unsigned)(rowk >> 32)) - T_MARGIN;
        for (int q = tid; q < k; q += 256) {
            unsigned long long e = lst[q];
            if (unsortable((unsigned)(e >> 32)) >= thr) {
                int p = atomicAdd(&scnt, 1);
                if (p < SCAP_) scand[p] = (int)(~(unsigned)(e & 0xFFFFFFFFull));
            }
        }
    }
    __syncthreads();
    bool scanall = full || (scnt > SCAP_);
    int kk = scanall ? NMEM_ : scnt;

    // early exit: a single shortlist candidate IS the argmax (exact semantics)
    if (!scanall && kk == 1) {
        if (tid == 0) { int n = scand[0]; g_best[l] = n; g_pat[l] = mapping[n]; }
        return;
    }

    const int py = l / LWID, px = l - (l / LWID) * LWID;
    float bestv = -3.4e38f; int bestn = 0x7FFFFFFF;
    for (int q = 0; q < kk; q++) {
        int n = scanall ? q : scand[q];
        const float* mr = mem + (size_t)n * D_;
        float s = 0.f;
        for (int d = tid; d < D_; d += 256) {
            int c = d >> 10, rem = d & 1023, kh = rem >> 5, kw = rem & 31;
            int y = py + kh - PAD_, x = px + kw - PAD_;
            float p = ((unsigned)y < (unsigned)H_ && (unsigned)x < (unsigned)W_)
                      ? img[((size_t)y * W_ + x) * C_ + c] : 0.f;
            s = fmaf(p, mr[d], s);
        }
        #pragma unroll
        for (int sh = 32; sh >= 1; sh >>= 1) s += __shfl_xor(s, sh, 64);
        if (lane == 0) redf[wave] = s;
        __syncthreads();
        float tot = redf[0] + redf[1] + redf[2] + redf[3] + g_bias[n];
        __syncthreads();   // redf reused next iteration
        if (tot > bestv || (tot == bestv && n < bestn)) { bestv = tot; bestn = n; }
    }
    if (tid == 0) { g_best[l] = bestn; g_pat[l] = mapping[bestn]; }
}

// ---- gather-fold: coalesced, py-quartered for parallelism -------------------
__global__ __launch_bounds__(128)
void gather_fold(const float* __restrict__ mem2)
{
    const int y = blockIdx.x;
    const int c = blockIdx.y;
    const int q = blockIdx.z;
    const int x = threadIdx.x;            // 0..127
    const int wv = x >> 6;

    const int py_lo = max(0, y - 21);
    const int py_hi = min(LWID - 1, y + PAD_);
    const int p0 = py_lo + q * 8;
    const int p1 = min(p0 + 8, py_hi + 1);
    const int nrows = (p1 > p0) ? (p1 - p0) : 0;

    __shared__ int patS[8 * LWID];
    for (int i = x; i < nrows * LWID; i += 128) {
        int rr = i / LWID, cc = i - rr * LWID;
        patS[i] = g_pat[(p0 + rr) * LWID + cc];
    }
    __syncthreads();

    const int slo = wv ? 43 : 0;
    const int shi = wv ? 116 : 73;

    float acc = 0.f;
    for (int py = p0; py < p1; ++py) {
        const int kh = y + PAD_ - py;                 // 0..31
        const int dbase = c * 1024 + kh * 32;
        const int* prow = &patS[(py - p0) * LWID];
        for (int s = slo; s <= shi; ++s) {
            int d = x + PAD_ - s;                     // lane-linear
            if ((unsigned)d < 32u)
                acc += mem2[(size_t)prow[s] * D_ + dbase + d];
        }
    }
    g_part[q][((size_t)y * W_ + x) * C_ + c] = acc;
}

// ---- sum partials + global max ----------------------------------------------
__global__ __launch_bounds__(256)
void maxfind(float* __restrict__ out)
{
    int i = blockIdx.x * 256 + threadIdx.x;           // 192*256 == 49152 exact
    float v = g_part[0][i] + g_part[1][i] + g_part[2][i] + g_part[3][i];
    out[i] = v;
    float m = v;
    #pragma unroll
    for (int s = 32; s >= 1; s >>= 1) m = fmaxf(m, __shfl_xor(m, s, 64));
    if ((threadIdx.x & 63) == 0) atomicMax(&g_max, sortable(m));
}

__global__ __launch_bounds__(256)
void normalize_k(float* __restrict__ out)
{
    int i = blockIdx.x * 256 + threadIdx.x;
    float mx = unsortable(g_max);
    out[i] = out[i] / mx;
}

extern "C" void kernel_launch(void* const* d_in, const int* in_sizes, int n_in,
                              void* d_out, int out_size, void* d_ws, size_t ws_size,
                              hipStream_t stream)
{
    const float* img     = (const float*)d_in[0];   // (128,128,3)
    const float* mem     = (const float*)d_in[1];   // (4096,3072)
    const float* mem2    = (const float*)d_in[2];   // (4096,3072)
    const int*   mapping = (const int*)d_in[3];     // (4096,)
    float* out = (float*)d_out;                     // (128,128,3)

    prep<<<NMEM_ + LPAD, 256, 0, stream>>>(img, mem);
    gemm_scores<<<(NMEM_ / 256) * (LPAD / 128), 256, 0, stream>>>();
    reduce_rescue<<<L_, 256, 0, stream>>>(img, mem, mapping);
    gather_fold<<<dim3(H_, C_, 4), 128, 0, stream>>>(mem2);
    maxfind<<<192, 256, 0, stream>>>(out);
    normalize_k<<<192, 256, 0, stream>>>(out);
}

// Round 6
// 535.125 us; speedup vs baseline: 1.1847x; 1.1847x over previous
//
#include <hip/hip_runtime.h>

// Problem constants
#define H_    128
#define W_    128
#define C_    3
#define PAD_  10
#define LWID  117          // LW = LH = 117
#define L_    13689        // LH*LW
#define LPAD  13696        // 107 * 128
#define D_    3072         // C*KH*KW
#define NMEM_ 4096

#define T_MARGIN 3.0f      // candidate margin; i8-quant score err sigma ~0.32 (9 sigma)
#define CAP_     256       // per-row candidate list capacity
#define SCAP_    64        // rescue shortlist capacity (expected ~1.4)

#define PSCALE 127.0f      // patch quant scale (p in [0,1))
#define MSCALE 32.0f       // mem quant scale (clip +-3.97)
#define INVS   (1.0f / (PSCALE * MSCALE))

typedef int   intx4  __attribute__((ext_vector_type(4)));

// Static device-side scratch (bss) — no d_ws dependency
__device__ int                g_best[L_];
__device__ int                g_pat[L_];     // mapping[g_best[l]] resolved in rescue
__device__ float              g_bias[NMEM_];
__device__ unsigned           g_max;
__device__ int                g_cnt[LPAD];
__device__ unsigned long long g_list[(size_t)LPAD * CAP_];   // 28 MB
__device__ char               g_A[(size_t)LPAD * D_];        // 42 MB i8 patches
__device__ char               g_B[(size_t)NMEM_ * D_];       // 12.6 MB i8 mem
__device__ float              g_part[4][H_ * W_ * C_];       // fold partials, 786 KB

__device__ __forceinline__ unsigned sortable(float f) {
    unsigned b = __float_as_uint(f);
    return (b & 0x80000000u) ? ~b : (b | 0x80000000u);
}
__device__ __forceinline__ float unsortable(unsigned u) {
    unsigned b = (u & 0x80000000u) ? (u & 0x7FFFFFFFu) : ~u;
    return __uint_as_float(b);
}
__device__ __forceinline__ unsigned long long packkey(float s, int n) {
    // max-key == max score; ties -> smaller n (jnp.argmax first-index)
    return ((unsigned long long)sortable(s) << 32) | (unsigned)(~n);
}

// async global->LDS, 16 bytes per lane (global_load_lds_dwordx4)
__device__ __forceinline__ void gl_lds16(const char* g, char* l) {
    __builtin_amdgcn_global_load_lds(
        (const __attribute__((address_space(1))) unsigned int*)(g),
        (__attribute__((address_space(3))) unsigned int*)(l), 16, 0, 0);
}

__device__ __forceinline__ int pack4(int a, int b, int c, int d) {
    return (a & 255) | ((b & 255) << 8) | ((c & 255) << 16) | ((d & 255) << 24);
}

// ---- fused prep: quantize mem + bias | build+quantize patches | zero cnts ---
__global__ __launch_bounds__(256)
void prep(const float* __restrict__ img, const float* __restrict__ mem)
{
    const int b = blockIdx.x;
    if (b < NMEM_) {
        const int n = b;
        const float4* row = (const float4*)(mem + (size_t)n * D_);
        int* q8 = (int*)(g_B + (size_t)n * D_);
        float s = 0.f;
        for (int q = threadIdx.x; q < D_ / 4; q += 256) {
            float4 v = row[q];
            int q0 = __float2int_rn(fminf(fmaxf(v.x * MSCALE, -127.f), 127.f));
            int q1 = __float2int_rn(fminf(fmaxf(v.y * MSCALE, -127.f), 127.f));
            int q2 = __float2int_rn(fminf(fmaxf(v.z * MSCALE, -127.f), 127.f));
            int q3 = __float2int_rn(fminf(fmaxf(v.w * MSCALE, -127.f), 127.f));
            q8[q] = pack4(q0, q1, q2, q3);
            s = fmaf(v.x, v.x, s); s = fmaf(v.y, v.y, s);
            s = fmaf(v.z, v.z, s); s = fmaf(v.w, v.w, s);
        }
        #pragma unroll
        for (int m = 32; m >= 1; m >>= 1) s += __shfl_down(s, m, 64);
        __shared__ float red[4];
        int lane = threadIdx.x & 63, w = threadIdx.x >> 6;
        if (lane == 0) red[w] = s;
        __syncthreads();
        if (threadIdx.x == 0) g_bias[n] = -0.5f * (red[0] + red[1] + red[2] + red[3]);
    } else {
        const int l = b - NMEM_;            // 0..LPAD-1 (pad rows -> zeros)
        if (threadIdx.x == 0) { g_cnt[l] = 0; if (l == 0) g_max = 0u; }
        const int py = l / LWID, px = l - (l / LWID) * LWID;
        const bool vl = l < L_;
        int* q8 = (int*)(g_A + (size_t)l * D_);
        for (int q = threadIdx.x; q < D_ / 4; q += 256) {
            int d = q * 4;
            int c = d >> 10, rem = d & 1023, kh = rem >> 5, kw0 = rem & 31;
            int qv[4] = {0, 0, 0, 0};
            if (vl) {
                int y = py + kh - PAD_;
                if ((unsigned)y < (unsigned)H_) {
                    int xb = px + kw0 - PAD_;
                    const float* ip = img + (size_t)y * (W_ * C_) + c;
                    #pragma unroll
                    for (int t = 0; t < 4; t++) {
                        int x = xb + t;
                        if ((unsigned)x < (unsigned)W_)
                            qv[t] = __float2int_rn(ip[x * C_] * PSCALE);
                    }
                }
            }
            q8[q] = pack4(qv[0], qv[1], qv[2], qv[3]);
        }
    }
}

// ---- i8 MFMA GEMM, 128l x 128n tile, BK=128, 4 blocks/CU --------------------
// Round-6: occupancy play. Evidence so far: scheduling (r1-3) null; moving A
// off LDS (r5) regressed via doubled A fetch + VMEM latency; nothing is
// saturated (MFMA 24%, VALU 16%, LDS ~40%, HBM 9%) and Occupancy ~18% ->
// latency-bound with too few independent waves. Halve the tile: 128x128,
// LDS 32.5KB (sA 16 + sB 16 + bias 0.5), acc 4x4 per wave (64 VGPR) ->
// __launch_bounds__(256,4): 4 blocks/CU resident (130KB LDS, VGPR<=128),
// 16 waves/CU at independent loop phases to hide gl_lds/ds_read latency.
// LDS-per-MFMA rises 33% but LDS pipe was only ~40% busy. Grid 107x32=3424
// blocks (13.4 rounds -> tail amortized). XCD decode: b&7 -> nt group of 4,
// per-XCD B slice 4x128x3072 = 1.57MB (L2-resident).
__global__ __launch_bounds__(256, 4)
void gemm_scores()
{
    __shared__ char sA[128 * 128];   // 16 KB
    __shared__ char sB[128 * 128];   // 16 KB
    __shared__ float biasS[128];

    const int tid = threadIdx.x;
    const int b = blockIdx.x;
    const int nt = (b & 7) * 4 + ((b >> 3) & 3);   // 0..31
    const int lt = b >> 5;                          // 0..106
    const int l0 = lt * 128;
    const int n0 = nt * 128;

    if (tid < 128) biasS[tid] = g_bias[n0 + tid];

    const int wave = tid >> 6, lane = tid & 63;
    const int wy = wave >> 1, wx = wave & 1;      // wave tile: 64l x 64n
    const int mrow = lane & 15, kgrp = lane >> 4;

    intx4 acc[4][4];
    #pragma unroll
    for (int i = 0; i < 4; i++)
        #pragma unroll
        for (int j = 0; j < 4; j++) acc[i][j] = (intx4){0, 0, 0, 0};

    const char* Ab = g_A + (size_t)l0 * D_;
    const char* Bb = g_B + (size_t)n0 * D_;

    // Staging: A 1024 + B 1024 16B-chunks per iter (4+4 per thread).
    // Chunk c -> row=c>>3, sub-block jj=(c&7)^(row&7) (XOR swizzle ->
    // ds_read_b128 lands 2 lanes/16B-slot = conflict-free).
    for (int d0 = 0; d0 < D_; d0 += 128) {
        __syncthreads();
        #pragma unroll
        for (int t = 0; t < 4; t++) {
            int c = tid + 256 * t;
            int row = c >> 3;
            int jj = (c & 7) ^ (row & 7);
            gl_lds16(Ab + (size_t)row * D_ + d0 + jj * 16, &sA[c * 16]);
        }
        #pragma unroll
        for (int t = 0; t < 4; t++) {
            int c = tid + 256 * t;
            int row = c >> 3;
            int jj = (c & 7) ^ (row & 7);
            gl_lds16(Bb + (size_t)row * D_ + d0 + jj * 16, &sB[c * 16]);
        }
        __syncthreads();

        #pragma unroll
        for (int ks = 0; ks < 2; ks++) {
            intx4 a[4], bf[4];
            #pragma unroll
            for (int i = 0; i < 4; i++) {
                int ra = wy * 64 + i * 16 + mrow;
                int ca = ra * 8 + ((ks * 4 + kgrp) ^ (ra & 7));
                a[i] = *(const intx4*)&sA[ca * 16];
            }
            #pragma unroll
            for (int j = 0; j < 4; j++) {
                int rb = wx * 64 + j * 16 + mrow;
                int cb = rb * 8 + ((ks * 4 + kgrp) ^ (rb & 7));
                bf[j] = *(const intx4*)&sB[cb * 16];
            }
            #pragma unroll
            for (int i = 0; i < 4; i++)
                #pragma unroll
                for (int j = 0; j < 4; j++)
                    acc[i][j] = __builtin_amdgcn_mfma_i32_16x16x64_i8(a[i], bf[j], acc[i][j], 0, 0, 0);
        }
    }

    // epilogue. C/D layout: col = lane&15 (mrow), row = kgrp*4 + reg.
    // 16-lane group max covers this wave's full 64-col n-slice; threshold is
    // a per-slice lower bound of the row max (extra candidates are pruned in
    // reduce_rescue against the global row max — semantics unchanged).
    #pragma unroll
    for (int i = 0; i < 4; i++) {
        #pragma unroll
        for (int r = 0; r < 4; r++) {
            const int lrow = l0 + wy * 64 + i * 16 + kgrp * 4 + r;
            float sc[4];
            #pragma unroll
            for (int j = 0; j < 4; j++)
                sc[j] = (float)acc[i][j][r] * INVS + biasS[wx * 64 + j * 16 + mrow];
            float bestv = sc[0]; int bestj = 0;
            #pragma unroll
            for (int j = 1; j < 4; j++)
                if (sc[j] > bestv) { bestv = sc[j]; bestj = j; }
            unsigned long long key = packkey(bestv, n0 + wx * 64 + bestj * 16 + mrow);
            #pragma unroll
            for (int m = 1; m < 16; m <<= 1) {
                unsigned long long o = __shfl_xor(key, m, 64);
                if (o > key) key = o;
            }
            float thr = unsortable((unsigned)(key >> 32)) - T_MARGIN;
            #pragma unroll
            for (int j = 0; j < 4; j++) {
                if (sc[j] >= thr) {
                    int pos = atomicAdd(&g_cnt[lrow], 1);
                    if (pos < CAP_)
                        g_list[(size_t)lrow * CAP_ + pos] =
                            packkey(sc[j], n0 + wx * 64 + j * 16 + mrow);
                }
            }
        }
    }
}

// ---- per-row shortlist + exact fp32 rescore + pattern resolve ---------------
// kk==1 early exit (round-4, verified): a single shortlist candidate IS the
// argmax — skip the 12KB mem-row read + img gathers. Bit-identical output.
__global__ __launch_bounds__(256)
void reduce_rescue(const float* __restrict__ img, const float* __restrict__ mem,
                   const int* __restrict__ mapping)
{
    const int l = blockIdx.x;
    const int tid = threadIdx.x;
    const int lane = tid & 63, wave = tid >> 6;

    __shared__ unsigned long long redk[4];
    __shared__ float redf[4];
    __shared__ int   scand[SCAP_];
    __shared__ int   scnt;

    if (tid == 0) scnt = 0;
    int cnt = g_cnt[l];
    bool full = cnt > CAP_;
    __syncthreads();

    if (!full) {
        int k = cnt;
        const unsigned long long* lst = g_list + (size_t)l * CAP_;
        unsigned long long mk = 0ull;
        for (int q = tid; q < k; q += 256) {
            unsigned long long e = lst[q];
            if (e > mk) mk = e;
        }
        #pragma unroll
        for (int m = 32; m >= 1; m >>= 1) {
            unsigned long long o = __shfl_xor(mk, m, 64);
            if (o > mk) mk = o;
        }
        if (lane == 0) redk[wave] = mk;
        __syncthreads();
        unsigned long long rowk = redk[0];
        #pragma unroll
        for (int w = 1; w < 4; w++) if (redk[w] > rowk) rowk = redk[w];
        float thr = unsortable((unsigned)(rowk >> 32)) - T_MARGIN;
        for (int q = tid; q < k; q += 256) {
            unsigned long long e = lst[q];
            if (unsortable((unsigned)(e >> 32)) >= thr) {
                int p = atomicAdd(&scnt, 1);
                if (p < SCAP_) scand[p] = (int)(~(unsigned)(e & 0xFFFFFFFFull));
            }
        }
    }
    __syncthreads();
    bool scanall = full || (scnt > SCAP_);
    int kk = scanall ? NMEM_ : scnt;

    // early exit: a single shortlist candidate IS the argmax (exact semantics)
    if (!scanall && kk == 1) {
        if (tid == 0) { int n = scand[0]; g_best[l] = n; g_pat[l] = mapping[n]; }
        return;
    }

    const int py = l / LWID, px = l - (l / LWID) * LWID;
    float bestv = -3.4e38f; int bestn = 0x7FFFFFFF;
    for (int q = 0; q < kk; q++) {
        int n = scanall ? q : scand[q];
        const float* mr = mem + (size_t)n * D_;
        float s = 0.f;
        for (int d = tid; d < D_; d += 256) {
            int c = d >> 10, rem = d & 1023, kh = rem >> 5, kw = rem & 31;
            int y = py + kh - PAD_, x = px + kw - PAD_;
            float p = ((unsigned)y < (unsigned)H_ && (unsigned)x < (unsigned)W_)
                      ? img[((size_t)y * W_ + x) * C_ + c] : 0.f;
            s = fmaf(p, mr[d], s);
        }
        #pragma unroll
        for (int sh = 32; sh >= 1; sh >>= 1) s += __shfl_xor(s, sh, 64);
        if (lane == 0) redf[wave] = s;
        __syncthreads();
        float tot = redf[0] + redf[1] + redf[2] + redf[3] + g_bias[n];
        __syncthreads();   // redf reused next iteration
        if (tot > bestv || (tot == bestv && n < bestn)) { bestv = tot; bestn = n; }
    }
    if (tid == 0) { g_best[l] = bestn; g_pat[l] = mapping[bestn]; }
}

// ---- gather-fold: coalesced, py-quartered for parallelism -------------------
__global__ __launch_bounds__(128)
void gather_fold(const float* __restrict__ mem2)
{
    const int y = blockIdx.x;
    const int c = blockIdx.y;
    const int q = blockIdx.z;
    const int x = threadIdx.x;            // 0..127
    const int wv = x >> 6;

    const int py_lo = max(0, y - 21);
    const int py_hi = min(LWID - 1, y + PAD_);
    const int p0 = py_lo + q * 8;
    const int p1 = min(p0 + 8, py_hi + 1);
    const int nrows = (p1 > p0) ? (p1 - p0) : 0;

    __shared__ int patS[8 * LWID];
    for (int i = x; i < nrows * LWID; i += 128) {
        int rr = i / LWID, cc = i - rr * LWID;
        patS[i] = g_pat[(p0 + rr) * LWID + cc];
    }
    __syncthreads();

    const int slo = wv ? 43 : 0;
    const int shi = wv ? 116 : 73;

    float acc = 0.f;
    for (int py = p0; py < p1; ++py) {
        const int kh = y + PAD_ - py;                 // 0..31
        const int dbase = c * 1024 + kh * 32;
        const int* prow = &patS[(py - p0) * LWID];
        for (int s = slo; s <= shi; ++s) {
            int d = x + PAD_ - s;                     // lane-linear
            if ((unsigned)d < 32u)
                acc += mem2[(size_t)prow[s] * D_ + dbase + d];
        }
    }
    g_part[q][((size_t)y * W_ + x) * C_ + c] = acc;
}

// ---- sum partials + global max ----------------------------------------------
__global__ __launch_bounds__(256)
void maxfind(float* __restrict__ out)
{
    int i = blockIdx.x * 256 + threadIdx.x;           // 192*256 == 49152 exact
    float v = g_part[0][i] + g_part[1][i] + g_part[2][i] + g_part[3][i];
    out[i] = v;
    float m = v;
    #pragma unroll
    for (int s = 32; s >= 1; s >>= 1) m = fmaxf(m, __shfl_xor(m, s, 64));
    if ((threadIdx.x & 63) == 0) atomicMax(&g_max, sortable(m));
}

__global__ __launch_bounds__(256)
void normalize_k(float* __restrict__ out)
{
    int i = blockIdx.x * 256 + threadIdx.x;
    float mx = unsortable(g_max);
    out[i] = out[i] / mx;
}

extern "C" void kernel_launch(void* const* d_in, const int* in_sizes, int n_in,
                              void* d_out, int out_size, void* d_ws, size_t ws_size,
                              hipStream_t stream)
{
    const float* img     = (const float*)d_in[0];   // (128,128,3)
    const float* mem     = (const float*)d_in[1];   // (4096,3072)
    const float* mem2    = (const float*)d_in[2];   // (4096,3072)
    const int*   mapping = (const int*)d_in[3];     // (4096,)
    float* out = (float*)d_out;                     // (128,128,3)

    prep<<<NMEM_ + LPAD, 256, 0, stream>>>(img, mem);
    gemm_scores<<<(NMEM_ / 128) * (LPAD / 128), 256, 0, stream>>>();
    reduce_rescue<<<L_, 256, 0, stream>>>(img, mem, mapping);
    gather_fold<<<dim3(H_, C_, 4), 128, 0, stream>>>(mem2);
    maxfind<<<192, 256, 0, stream>>>(out);
    normalize_k<<<192, 256, 0, stream>>>(out);
}